// Round 1
// baseline (117.456 us; speedup 1.0000x reference)
//
#include <hip/hip_runtime.h>
#include <cstdint>
#include <cstddef>

#define BB 512
#define TT 8192
#define TW 256          // u32 spike words per row-channel (TT/32)
#define KWIN 5
#define PADROW 8448     // 8192 + 4 floats pad per 128-float block (64 blocks)

static __device__ __forceinline__ float fract_f(float x) {
#if __has_builtin(__builtin_amdgcn_fractf)
    return __builtin_amdgcn_fractf(x);
#else
    return x - floorf(x);
#endif
}

// ---------------------------------------------------------------------------
// FUSED kernel: 512 blocks (one per batch row) x 256 threads (4 waves).
// LDS = 2 padded row buffers (67.6 KB) + 3x256 spike words (3 KB) -> 70.8 KB
// -> 2 blocks/CU -> ALL 512 blocks resident (one occupancy round; the old
// 2-kernel version ran 1536 blocks in 2 rounds with zero stage/chain overlap).
// Channel pipeline:
//   stage ch0 (all 4 waves)  | barrier
//   wave0: chain ch0         | waves1-3: stage ch1   | barrier
//   wave0: chain ch1         | waves1-3: stage ch2   | barrier
//   wave0: chain ch2         |                       | barrier
//   all 256: presence/ntab/htab -> sal write + streaming top-5 -> mu
// Spike words live in LDS (removes the 1.5MB write + 1.5MB read round trip
// and the second kernel launch gap).
// Chain math is VERBATIM from the validated rounds 6-7 kernel: unfused
// mul+add (numpy's two roundings) + exact v_fract, 128-step warm-up
// (0.7^128 ~ 2e-20 contraction => bit-exact state collapse), 16-float
// register groups via 4x ds_read_b128 prefetched one group ahead. Padded
// layout addr(p) = p + 4*(p>>7): lane l's keep window = 132l (16B-aligned),
// warm-up window = 132(l-1); stride 132 floats == 4 dwords mod 32 == the
// structural-minimum bank pattern for ds_read_b128.
// ---------------------------------------------------------------------------
__global__ __launch_bounds__(256, 2)
void fused_lif_salience_kernel(const float* __restrict__ amp,
                               const float* __restrict__ pitch,
                               const float* __restrict__ boundary,
                               const float* __restrict__ decay,
                               const float* __restrict__ weights,
                               float* __restrict__ out)
{
    const int b   = blockIdx.x;          // batch row
    const int tid = threadIdx.x;         // 0..255
    const int wv  = tid >> 6;            // wave id 0..3
    const int l   = tid & 63;            // lane in wave

    __shared__ __align__(16) float X[2][PADROW];       // 67,584 B
    __shared__ __align__(16) uint32_t words[3 * TW];   //  3,072 B
    __shared__ uint32_t spres[4];
    __shared__ float ntab[8];
    __shared__ uint32_t htab[8];
    __shared__ unsigned long long red[4];
    __shared__ unsigned long long wins;

    const float* __restrict__ amp_r = amp      + (size_t)b * TT;
    const float* __restrict__ pit_r = pitch    + (size_t)b * TT;
    const float* __restrict__ bnd_r = boundary + (size_t)b * TT;

    const float d0 = decay[0], d1 = decay[1], d2 = decay[2];

    // ---- stage channel 0 into X[0]: all 256 threads, 8 float4 each ----
    {
        const float4* s4 = reinterpret_cast<const float4*>(amp_r);
        float4 st[8];
#pragma unroll
        for (int i = 0; i < 8; ++i) st[i] = s4[tid + 256 * i];
#pragma unroll
        for (int i = 0; i < 8; ++i) {
            const int j0 = 4 * (tid + 256 * i);
            const int a0 = j0 + 4 * (j0 >> 7);          // padded, 16B-aligned
            *reinterpret_cast<float4*>(&X[0][a0]) = st[i];
        }
    }
    __syncthreads();

    // 16-float group loader (4x ds_read_b128), 16B-aligned by construction
    auto ldg = [](float4* dst, const float* p) {
#pragma unroll
        for (int i = 0; i < 4; ++i)
            dst[i] = *reinterpret_cast<const float4*>(p + 4 * i);
    };

    // 64-lane LIF chain for one channel: 128 warm-up + 128 keep steps,
    // register double-buffered group prefetch. Bit-identical to rounds 6-7.
    auto chain = [&](const float* Xb, const float dv, uint32_t* wdst) {
        float v = 0.0f;
        // warm-up: 128 discarded steps
        {
            const bool z = (l == 0);
            const float* wp = &Xb[z ? 0 : 132 * (l - 1)];
            float4 A[4], B[4];
            ldg(A, wp);
#define WSTEP(xx)                                               \
            {                                                   \
                float x = (xx);                                 \
                if (z) x = 0.0f;                                \
                float t2 = __fadd_rn(__fmul_rn(dv, v), x);      \
                v = fract_f(t2);                                \
            }
#pragma unroll
            for (int u = 0; u < 8; u += 2) {
                ldg(B, wp + 16 * (u + 1));
#pragma unroll
                for (int i = 0; i < 4; ++i) {
                    WSTEP(A[i].x) WSTEP(A[i].y) WSTEP(A[i].z) WSTEP(A[i].w)
                }
                if (u + 2 < 8) ldg(A, wp + 16 * (u + 2));
#pragma unroll
                for (int i = 0; i < 4; ++i) {
                    WSTEP(B[i].x) WSTEP(B[i].y) WSTEP(B[i].z) WSTEP(B[i].w)
                }
            }
#undef WSTEP
        }
        // keep: 128 exact steps, spike bits
        uint32_t w[4];
        {
            const float* kp = &Xb[132 * l];
            float4 A[4], B[4];
            float bs;
#define KSTEP(xx)                                               \
            {                                                   \
                float t2 = __fadd_rn(__fmul_rn(dv, v), (xx));   \
                float nv = fract_f(t2);                         \
                bs = __builtin_fmaf(2.0f, bs, t2 - nv);         \
                v = nv;                                         \
            }
            ldg(A, kp);
#pragma unroll
            for (int q = 0; q < 4; ++q) {
                ldg(B, kp + 32 * q + 16);
                bs = 0.0f;
#pragma unroll
                for (int i = 0; i < 4; ++i) {
                    KSTEP(A[i].x) KSTEP(A[i].y) KSTEP(A[i].z) KSTEP(A[i].w)
                }
                const uint32_t hi = (uint32_t)bs;
                if (q < 3) ldg(A, kp + 32 * q + 32);
                bs = 0.0f;
#pragma unroll
                for (int i = 0; i < 4; ++i) {
                    KSTEP(B[i].x) KSTEP(B[i].y) KSTEP(B[i].z) KSTEP(B[i].w)
                }
                w[q] = (hi << 16) | (uint32_t)bs;
            }
#undef KSTEP
        }
        *reinterpret_cast<uint4*>(wdst + 4 * l) = make_uint4(w[0], w[1], w[2], w[3]);
    };

    // stage one row with waves 1-3 (192 threads): 10 float4 each + 128
    // threads take an 11th (2048 = 192*10 + 128). Static reg indices only.
    auto stage192 = [&](float* Xb, const float* src) {
        const int t2 = tid - 64;                        // 0..191
        const float4* s4 = reinterpret_cast<const float4*>(src);
        float4 st[10];
#pragma unroll
        for (int i = 0; i < 10; ++i) st[i] = s4[t2 + 192 * i];
        float4 ex;
        const bool e = (t2 < 128);
        if (e) ex = s4[t2 + 1920];
#pragma unroll
        for (int i = 0; i < 10; ++i) {
            const int j0 = 4 * (t2 + 192 * i);
            const int a0 = j0 + 4 * (j0 >> 7);
            *reinterpret_cast<float4*>(&Xb[a0]) = st[i];
        }
        if (e) {
            const int j0 = 4 * (t2 + 1920);
            const int a0 = j0 + 4 * (j0 >> 7);
            *reinterpret_cast<float4*>(&Xb[a0]) = ex;
        }
    };

    // ---- pipelined slots: chain(c) overlaps stage(c+1) ----
    if (wv == 0) chain(X[0], d0, &words[0]);
    else         stage192(X[1], pit_r);
    __syncthreads();

    if (wv == 0) chain(X[1], d1, &words[TW]);
    else         stage192(X[0], bnd_r);
    __syncthreads();

    if (wv == 0) chain(X[0], d2, &words[2 * TW]);
    __syncthreads();

    // -----------------------------------------------------------------------
    // Salience + top-k phase (verbatim rounds 5-7 logic; words already in LDS)
    // -----------------------------------------------------------------------
    float* sal_out = out + 512 + (size_t)b * TT;
    const float w0 = weights[0], w1 = weights[1], w2 = weights[2];

    uint32_t pres = 0;
#pragma unroll
    for (int j = 0; j < 8; ++j) {
        const int t0 = 4 * tid + 1024 * j;
        const int wi = t0 >> 5;
        const uint32_t wa = words[wi], wp = words[TW + wi], wq = words[2 * TW + wi];
#pragma unroll
        for (int k = 0; k < 4; ++k) {
            const int sh = 31 - ((t0 & 31) + k);
            const uint32_t idx = ((wa >> sh) & 1u)
                               | (((wp >> sh) & 1u) << 1)
                               | (((wq >> sh) & 1u) << 2);
            pres |= (1u << idx);
        }
    }
#pragma unroll
    for (int off = 32; off; off >>= 1)
        pres |= __shfl_down(pres, off);
    if ((tid & 63) == 0) spres[tid >> 6] = pres;
    __syncthreads();

    if (tid < 8) {
        const uint32_t p = spres[0] | spres[1] | spres[2] | spres[3];
        float s0 = (float)(tid & 1), s1 = (float)((tid >> 1) & 1), s2 = (float)(tid >> 2);
        float tv = __fadd_rn(__fadd_rn(__fmul_rn(w0, s0), __fmul_rn(w1, s1)),
                             __fmul_rn(w2, s2));
        float m = ((p >> tid) & 1u) ? tv : -INFINITY;
        m = fmaxf(m, __shfl_xor(m, 1));
        m = fmaxf(m, __shfl_xor(m, 2));
        m = fmaxf(m, __shfl_xor(m, 4));
        const float denom = __fadd_rn(m, 1e-6f);
        float nv = tv / denom;               // ONE IEEE divide per table entry
        ntab[tid] = nv;
        uint32_t ub = __float_as_uint(nv);
        htab[tid] = (ub & 0x80000000u) ? ~ub : (ub | 0x80000000u);
    }
    __syncthreads();

    unsigned long long t5[5] = {0ull, 0ull, 0ull, 0ull, 0ull};
#pragma unroll
    for (int j = 0; j < 8; ++j) {
        const int t0 = 4 * tid + 1024 * j;
        const int wi = t0 >> 5;
        const uint32_t wa = words[wi], wp = words[TW + wi], wq = words[2 * TW + wi];
        float4 q;
        float* qp = &q.x;
#pragma unroll
        for (int k = 0; k < 4; ++k) {
            const int sh = 31 - ((t0 & 31) + k);
            const uint32_t idx = ((wa >> sh) & 1u)
                               | (((wp >> sh) & 1u) << 1)
                               | (((wq >> sh) & 1u) << 2);
            qp[k] = ntab[idx];
            unsigned long long key = ((unsigned long long)htab[idx] << 32)
                                   | (unsigned long long)(uint32_t)(TT - 1 - (t0 + k));
            if (key > t5[4]) {
#pragma unroll
                for (int i = 0; i < 5; ++i) {
                    bool g = key > t5[i];
                    unsigned long long o = t5[i];
                    t5[i] = g ? key : o;
                    key   = g ? o : key;
                }
            }
        }
        *reinterpret_cast<float4*>(sal_out + t0) = q;
    }

    float vsum = 0.0f;
    for (int r = 0; r < KWIN; ++r) {
        unsigned long long cand = t5[0];
#pragma unroll
        for (int off = 32; off; off >>= 1) {
            unsigned long long o = __shfl_down(cand, off);
            if (o > cand) cand = o;
        }
        __syncthreads();
        if ((tid & 63) == 0) red[tid >> 6] = cand;
        __syncthreads();
        if (tid == 0) {
            unsigned long long m = red[0];
            if (red[1] > m) m = red[1];
            if (red[2] > m) m = red[2];
            if (red[3] > m) m = red[3];
            wins = m;
        }
        __syncthreads();
        const unsigned long long w = wins;
        if (t5[0] == w) {
            t5[0] = t5[1]; t5[1] = t5[2]; t5[2] = t5[3]; t5[3] = t5[4]; t5[4] = 0ull;
        }
        if (tid == 0) {
            uint32_t hi = (uint32_t)(w >> 32);
            uint32_t fb = (hi & 0x80000000u) ? (hi & 0x7FFFFFFFu) : ~hi;
            vsum += __uint_as_float(fb);
            out[512 + (size_t)BB * TT + (size_t)b * KWIN + r] =
                (float)(int)(TT - 1 - (uint32_t)(w & 0xFFFFFFFFull));
        }
    }

    if (tid == 0) {
        out[b] = 0.5f + 2.0f * tanhf(1.8f * (vsum / 5.0f));
    }
}

extern "C" void kernel_launch(void* const* d_in, const int* in_sizes, int n_in,
                              void* d_out, int out_size, void* d_ws, size_t ws_size,
                              hipStream_t stream) {
    const float* amp      = (const float*)d_in[0];
    const float* pitch    = (const float*)d_in[1];
    const float* boundary = (const float*)d_in[2];
    const float* decay    = (const float*)d_in[3];
    const float* weights  = (const float*)d_in[4];
    float* out = (float*)d_out;

    fused_lif_salience_kernel<<<BB, 256, 0, stream>>>(amp, pitch, boundary,
                                                      decay, weights, out);
}

// Round 2
// 111.912 us; speedup vs baseline: 1.0495x; 1.0495x over previous
//
#include <hip/hip_runtime.h>
#include <cstdint>
#include <cstddef>

#define BB 512
#define TT 8192
#define TW 256          // u32 spike words per row-channel (TT/32)
#define KWIN 5

static __device__ __forceinline__ float fract_f(float x) {
#if __has_builtin(__builtin_amdgcn_fractf)
    return __builtin_amdgcn_fractf(x);
#else
    return x - floorf(x);
#endif
}

// ---------------------------------------------------------------------------
// Kernel 1: segmented LIF scan, REGISTER-RESIDENT (no LDS).
// 1536 blocks x 64 threads = one wave per (batch row, channel).
// Round-1 lesson: the fused 4-wave/71KB-LDS design collapsed parallelism
// (2 chain waves/CU, serial chains behind barriers) -> 59.6 us. Reverting
// to the 1536-wave structure and deleting LDS instead:
//   - lane l loads its keep window row[128l .. 128l+128) straight into
//     kr[32] (float4) — 512B lane stride; each 128B line is consumed
//     entirely by one lane's 8 consecutive dwordx4 loads (MSHR/L1 merge),
//     so HBM bytes stay minimal (48 MB total).
//   - warm-up input for lane l IS lane (l-1)'s keep window, so warm-up x
//     comes from __shfl_up(kr, 1) — bit-identical values to the old LDS
//     window read (lane 0 forced x=0, verbatim).
//   - zero LDS -> 8 blocks/CU (VGPR-limited), all 1536 waves resident in
//     ONE round (old: 33.8KB LDS -> 4/CU -> 1.5 rounds + stage barriers).
// Chain math UNFUSED mul+add (numpy's two roundings) + exact v_fract,
// 128-step warm-up (0.7^128 ~ 2e-20 => bit-exact state collapse) —
// identical op sequence to the validated baseline => identical spikes.
// ---------------------------------------------------------------------------
__global__ __launch_bounds__(64, 2)
void lif_scan_kernel(const float* __restrict__ amp,
                     const float* __restrict__ pitch,
                     const float* __restrict__ boundary,
                     const float* __restrict__ decay,
                     float* __restrict__ out)
{
    const int blk = blockIdx.x;          // 0..1535
    const int c   = blk >> 9;            // channel
    const int b   = blk & 511;           // batch row
    const int l   = threadIdx.x;         // 0..63
    const float* __restrict__ src =
        (c == 0 ? amp : (c == 1 ? pitch : boundary)) + (size_t)b * TT;
    const float dv = decay[c];

    // ---- load lane's keep window into registers: 32x global_load_dwordx4 ----
    const float4* s4 = reinterpret_cast<const float4*>(src);
    float4 kr[32];
#pragma unroll
    for (int j = 0; j < 32; ++j)
        kr[j] = s4[32 * l + j];

    float v = 0.0f;
    const bool z = (l == 0);

    // ---- warm-up: 128 discarded steps; x = neighbor's keep data via shfl ----
    {
        auto shuf4 = [](float4 a) {
            float4 r;
            r.x = __shfl_up(a.x, 1, 64);
            r.y = __shfl_up(a.y, 1, 64);
            r.z = __shfl_up(a.z, 1, 64);
            r.w = __shfl_up(a.w, 1, 64);
            return r;
        };
        float4 W0, W1;
        W0 = shuf4(kr[0]);
#define WSTEP(xx)                                               \
        {                                                       \
            float x = (xx);                                     \
            if (z) x = 0.0f;                                    \
            float t2 = __fadd_rn(__fmul_rn(dv, v), x);          \
            v = fract_f(t2);                                    \
        }
#pragma unroll
        for (int j = 0; j < 32; j += 2) {
            W1 = shuf4(kr[j + 1]);                  // prefetch next group
            WSTEP(W0.x) WSTEP(W0.y) WSTEP(W0.z) WSTEP(W0.w)
            if (j + 2 < 32) W0 = shuf4(kr[j + 2]);  // prefetch next-next
            WSTEP(W1.x) WSTEP(W1.y) WSTEP(W1.z) WSTEP(W1.w)
        }
#undef WSTEP
    }

    // ---- keep: 128 exact steps, spike bits, straight from registers ----
    uint32_t w[4];
    {
        float bs;
#define KSTEP(xx)                                               \
        {                                                       \
            float t2 = __fadd_rn(__fmul_rn(dv, v), (xx));       \
            float nv = fract_f(t2);                             \
            bs = __builtin_fmaf(2.0f, bs, t2 - nv);             \
            v = nv;                                             \
        }
#pragma unroll
        for (int q = 0; q < 4; ++q) {
            bs = 0.0f;
#pragma unroll
            for (int i = 0; i < 4; ++i) {
                const float4 a = kr[8 * q + i];
                KSTEP(a.x) KSTEP(a.y) KSTEP(a.z) KSTEP(a.w)
            }
            const uint32_t hi = (uint32_t)bs;
            bs = 0.0f;
#pragma unroll
            for (int i = 0; i < 4; ++i) {
                const float4 a = kr[8 * q + 4 + i];
                KSTEP(a.x) KSTEP(a.y) KSTEP(a.z) KSTEP(a.w)
            }
            w[q] = (hi << 16) | (uint32_t)bs;
        }
#undef KSTEP
    }

    // spike words: row b's sal head region, channel c's 256 words, lane l's 4
    uint32_t* wout = reinterpret_cast<uint32_t*>(out + 512 + (size_t)b * TT)
                   + c * TW;
    *reinterpret_cast<uint4*>(wout + 4 * l) = make_uint4(w[0], w[1], w[2], w[3]);
}

// ---------------------------------------------------------------------------
// Kernel 2: per-row normalize + top-k (512 blocks x 256 threads) — verbatim
// from the validated baseline (~2.2 us):
//   sal has only 8 possible values (w . s). Presence bitmask -> denom;
//   ONE IEEE divide per table entry (bitwise == numpy elementwise divide).
//   Streaming per-thread top-5 (5 u64 regs), then 5 block-max rounds.
//   Key = mono(val)<<32 | (8191-t)  => value desc, index asc (lax.top_k).
// ---------------------------------------------------------------------------
__global__ __launch_bounds__(256, 2)
void salience_topk_kernel(const float* __restrict__ weights,
                          float* __restrict__ out)
{
    const int b = blockIdx.x;
    const int tid = threadIdx.x;

    __shared__ uint32_t words[3 * TW];
    __shared__ uint32_t spres[4];
    __shared__ float ntab[8];
    __shared__ uint32_t htab[8];
    __shared__ unsigned long long red[4];
    __shared__ unsigned long long wins;

    float* sal_out = out + 512 + (size_t)b * TT;
    const uint32_t* wsrc = reinterpret_cast<const uint32_t*>(sal_out);

    words[tid]       = wsrc[tid];
    words[tid + 256] = wsrc[tid + 256];
    words[tid + 512] = wsrc[tid + 512];

    const float w0 = weights[0], w1 = weights[1], w2 = weights[2];
    __syncthreads();

    uint32_t pres = 0;
#pragma unroll
    for (int j = 0; j < 8; ++j) {
        const int t0 = 4 * tid + 1024 * j;
        const int wi = t0 >> 5;
        const uint32_t wa = words[wi], wp = words[TW + wi], wq = words[2 * TW + wi];
#pragma unroll
        for (int k = 0; k < 4; ++k) {
            const int sh = 31 - ((t0 & 31) + k);
            const uint32_t idx = ((wa >> sh) & 1u)
                               | (((wp >> sh) & 1u) << 1)
                               | (((wq >> sh) & 1u) << 2);
            pres |= (1u << idx);
        }
    }
#pragma unroll
    for (int off = 32; off; off >>= 1)
        pres |= __shfl_down(pres, off);
    if ((tid & 63) == 0) spres[tid >> 6] = pres;
    __syncthreads();

    if (tid < 8) {
        const uint32_t p = spres[0] | spres[1] | spres[2] | spres[3];
        float s0 = (float)(tid & 1), s1 = (float)((tid >> 1) & 1), s2 = (float)(tid >> 2);
        float tv = __fadd_rn(__fadd_rn(__fmul_rn(w0, s0), __fmul_rn(w1, s1)),
                             __fmul_rn(w2, s2));
        float m = ((p >> tid) & 1u) ? tv : -INFINITY;
        m = fmaxf(m, __shfl_xor(m, 1));
        m = fmaxf(m, __shfl_xor(m, 2));
        m = fmaxf(m, __shfl_xor(m, 4));
        const float denom = __fadd_rn(m, 1e-6f);
        float nv = tv / denom;               // ONE IEEE divide per table entry
        ntab[tid] = nv;
        uint32_t ub = __float_as_uint(nv);
        htab[tid] = (ub & 0x80000000u) ? ~ub : (ub | 0x80000000u);
    }
    __syncthreads();

    unsigned long long t5[5] = {0ull, 0ull, 0ull, 0ull, 0ull};
#pragma unroll
    for (int j = 0; j < 8; ++j) {
        const int t0 = 4 * tid + 1024 * j;
        const int wi = t0 >> 5;
        const uint32_t wa = words[wi], wp = words[TW + wi], wq = words[2 * TW + wi];
        float4 q;
        float* qp = &q.x;
#pragma unroll
        for (int k = 0; k < 4; ++k) {
            const int sh = 31 - ((t0 & 31) + k);
            const uint32_t idx = ((wa >> sh) & 1u)
                               | (((wp >> sh) & 1u) << 1)
                               | (((wq >> sh) & 1u) << 2);
            qp[k] = ntab[idx];
            unsigned long long key = ((unsigned long long)htab[idx] << 32)
                                   | (unsigned long long)(uint32_t)(TT - 1 - (t0 + k));
            if (key > t5[4]) {
#pragma unroll
                for (int i = 0; i < 5; ++i) {
                    bool g = key > t5[i];
                    unsigned long long o = t5[i];
                    t5[i] = g ? key : o;
                    key   = g ? o : key;
                }
            }
        }
        *reinterpret_cast<float4*>(sal_out + t0) = q;
    }

    float vsum = 0.0f;
    for (int r = 0; r < KWIN; ++r) {
        unsigned long long cand = t5[0];
#pragma unroll
        for (int off = 32; off; off >>= 1) {
            unsigned long long o = __shfl_down(cand, off);
            if (o > cand) cand = o;
        }
        __syncthreads();
        if ((tid & 63) == 0) red[tid >> 6] = cand;
        __syncthreads();
        if (tid == 0) {
            unsigned long long m = red[0];
            if (red[1] > m) m = red[1];
            if (red[2] > m) m = red[2];
            if (red[3] > m) m = red[3];
            wins = m;
        }
        __syncthreads();
        const unsigned long long w = wins;
        if (t5[0] == w) {
            t5[0] = t5[1]; t5[1] = t5[2]; t5[2] = t5[3]; t5[3] = t5[4]; t5[4] = 0ull;
        }
        if (tid == 0) {
            uint32_t hi = (uint32_t)(w >> 32);
            uint32_t fb = (hi & 0x80000000u) ? (hi & 0x7FFFFFFFu) : ~hi;
            vsum += __uint_as_float(fb);
            out[512 + (size_t)BB * TT + (size_t)b * KWIN + r] =
                (float)(int)(TT - 1 - (uint32_t)(w & 0xFFFFFFFFull));
        }
    }

    if (tid == 0) {
        out[b] = 0.5f + 2.0f * tanhf(1.8f * (vsum / 5.0f));
    }
}

extern "C" void kernel_launch(void* const* d_in, const int* in_sizes, int n_in,
                              void* d_out, int out_size, void* d_ws, size_t ws_size,
                              hipStream_t stream) {
    const float* amp      = (const float*)d_in[0];
    const float* pitch    = (const float*)d_in[1];
    const float* boundary = (const float*)d_in[2];
    const float* decay    = (const float*)d_in[3];
    const float* weights  = (const float*)d_in[4];
    float* out = (float*)d_out;

    lif_scan_kernel<<<3 * BB, 64, 0, stream>>>(amp, pitch, boundary, decay, out);
    salience_topk_kernel<<<BB, 256, 0, stream>>>(weights, out);
}

// Round 4
// 110.811 us; speedup vs baseline: 1.0600x; 1.0099x over previous
//
#include <hip/hip_runtime.h>
#include <cstdint>
#include <cstddef>

#define BB 512
#define TT 8192
#define TW 256          // u32 spike words per row-channel (TT/32)
#define KWIN 5

static __device__ __forceinline__ float fract_f(float x) {
#if __has_builtin(__builtin_amdgcn_fractf)
    return __builtin_amdgcn_fractf(x);
#else
    return x - floorf(x);
#endif
}

// ---------------------------------------------------------------------------
// FUSED kernel, parallel-chain edition. 512 blocks x 256 threads (4 waves).
// (Resubmission of Round-2 proposal — Round-3 bench died to an infra error
// "container failed twice" with no compile/validation/profile evidence.)
// Round-1 fusion failed because ONE wave ran all 3 chains serially behind
// staging barriers (2 chain-waves/CU). This version keeps Round-2's winning
// structure — 1536 independent register-resident chain waves, zero LDS
// staging, zero barriers during the scan — and only moves the top-k phase
// in-kernel:
//   waves 0..2: channel wv of row b. Lane l loads its keep window
//     row[128l..128l+128) straight into kr[32] (32x global_load_dwordx4,
//     512B lane stride; each 128B line fully consumed by one lane -> HBM
//     bytes stay 48 MB). Warm-up input for lane l IS lane (l-1)'s keep
//     window -> __shfl_up (bit-identical; lane 0 forced x=0). 128 warm-up
//     steps (0.7^128 ~ 2e-20 => bit-exact state collapse) + 128 keep steps.
//     Spike words -> LDS (was: 1.6MB HBM write + 3MB read round trip).
//   wave 3: sleeps at the barrier (chains are latency-bound; its issue
//     slots aren't needed) so the validated 256-thread top-k phase keeps
//     its exact 4x64 indexing.
//   one __syncthreads(), then salience/top-k phase VERBATIM from the
//   validated kernel 2 (presence bitmask -> 8-entry table, ONE IEEE divide
//   per entry, streaming per-thread top-5, 5 block-max rounds).
// Removes: second launch, k1->k2 dependency gap, spike-word HBM round trip.
// Chain math UNFUSED mul+add (numpy's two roundings) + exact v_fract —
// identical op sequence to the validated baseline => identical outputs.
// Occupancy: 2 blocks/CU (256 thr, <=256 VGPR) -> all 512 blocks resident;
// 1536 chain waves, same as the two-kernel version.
// ---------------------------------------------------------------------------
__global__ __launch_bounds__(256, 2)
void fused_lif_salience_kernel(const float* __restrict__ amp,
                               const float* __restrict__ pitch,
                               const float* __restrict__ boundary,
                               const float* __restrict__ decay,
                               const float* __restrict__ weights,
                               float* __restrict__ out)
{
    const int b   = blockIdx.x;          // batch row
    const int tid = threadIdx.x;         // 0..255
    const int wv  = tid >> 6;            // wave id 0..3
    const int l   = tid & 63;            // lane in wave

    __shared__ __align__(16) uint32_t words[3 * TW];   // 3 KB spike words
    __shared__ uint32_t spres[4];
    __shared__ float ntab[8];
    __shared__ uint32_t htab[8];
    __shared__ unsigned long long red[4];
    __shared__ unsigned long long wins;

    // ---- waves 0..2: one register-resident LIF chain each ----
    if (wv < 3) {
        const float* __restrict__ src =
            (wv == 0 ? amp : (wv == 1 ? pitch : boundary)) + (size_t)b * TT;
        const float dv = decay[wv];

        const float4* s4 = reinterpret_cast<const float4*>(src);
        float4 kr[32];
#pragma unroll
        for (int j = 0; j < 32; ++j)
            kr[j] = s4[32 * l + j];

        float v = 0.0f;
        const bool z = (l == 0);

        // warm-up: 128 discarded steps; x = neighbor's keep data via shfl
        {
            auto shuf4 = [](float4 a) {
                float4 r;
                r.x = __shfl_up(a.x, 1, 64);
                r.y = __shfl_up(a.y, 1, 64);
                r.z = __shfl_up(a.z, 1, 64);
                r.w = __shfl_up(a.w, 1, 64);
                return r;
            };
            float4 W0, W1;
            W0 = shuf4(kr[0]);
#define WSTEP(xx)                                               \
            {                                                   \
                float x = (xx);                                 \
                if (z) x = 0.0f;                                \
                float t2 = __fadd_rn(__fmul_rn(dv, v), x);      \
                v = fract_f(t2);                                \
            }
#pragma unroll
            for (int j = 0; j < 32; j += 2) {
                W1 = shuf4(kr[j + 1]);                  // prefetch next group
                WSTEP(W0.x) WSTEP(W0.y) WSTEP(W0.z) WSTEP(W0.w)
                if (j + 2 < 32) W0 = shuf4(kr[j + 2]);  // prefetch next-next
                WSTEP(W1.x) WSTEP(W1.y) WSTEP(W1.z) WSTEP(W1.w)
            }
#undef WSTEP
        }

        // keep: 128 exact steps, spike bits, straight from registers
        uint32_t w[4];
        {
            float bs;
#define KSTEP(xx)                                               \
            {                                                   \
                float t2 = __fadd_rn(__fmul_rn(dv, v), (xx));   \
                float nv = fract_f(t2);                         \
                bs = __builtin_fmaf(2.0f, bs, t2 - nv);         \
                v = nv;                                         \
            }
#pragma unroll
            for (int q = 0; q < 4; ++q) {
                bs = 0.0f;
#pragma unroll
                for (int i = 0; i < 4; ++i) {
                    const float4 a = kr[8 * q + i];
                    KSTEP(a.x) KSTEP(a.y) KSTEP(a.z) KSTEP(a.w)
                }
                const uint32_t hi = (uint32_t)bs;
                bs = 0.0f;
#pragma unroll
                for (int i = 0; i < 4; ++i) {
                    const float4 a = kr[8 * q + 4 + i];
                    KSTEP(a.x) KSTEP(a.y) KSTEP(a.z) KSTEP(a.w)
                }
                w[q] = (hi << 16) | (uint32_t)bs;
            }
#undef KSTEP
        }

        // spike words -> LDS (channel wv's 256 words, lane l's 4)
        *reinterpret_cast<uint4*>(&words[wv * TW + 4 * l]) =
            make_uint4(w[0], w[1], w[2], w[3]);
    }
    __syncthreads();

    // -----------------------------------------------------------------------
    // Salience + top-k phase (VERBATIM validated logic; words already in LDS)
    // -----------------------------------------------------------------------
    float* sal_out = out + 512 + (size_t)b * TT;
    const float w0 = weights[0], w1 = weights[1], w2 = weights[2];

    uint32_t pres = 0;
#pragma unroll
    for (int j = 0; j < 8; ++j) {
        const int t0 = 4 * tid + 1024 * j;
        const int wi = t0 >> 5;
        const uint32_t wa = words[wi], wp = words[TW + wi], wq = words[2 * TW + wi];
#pragma unroll
        for (int k = 0; k < 4; ++k) {
            const int sh = 31 - ((t0 & 31) + k);
            const uint32_t idx = ((wa >> sh) & 1u)
                               | (((wp >> sh) & 1u) << 1)
                               | (((wq >> sh) & 1u) << 2);
            pres |= (1u << idx);
        }
    }
#pragma unroll
    for (int off = 32; off; off >>= 1)
        pres |= __shfl_down(pres, off);
    if ((tid & 63) == 0) spres[tid >> 6] = pres;
    __syncthreads();

    if (tid < 8) {
        const uint32_t p = spres[0] | spres[1] | spres[2] | spres[3];
        float s0 = (float)(tid & 1), s1 = (float)((tid >> 1) & 1), s2 = (float)(tid >> 2);
        float tv = __fadd_rn(__fadd_rn(__fmul_rn(w0, s0), __fmul_rn(w1, s1)),
                             __fmul_rn(w2, s2));
        float m = ((p >> tid) & 1u) ? tv : -INFINITY;
        m = fmaxf(m, __shfl_xor(m, 1));
        m = fmaxf(m, __shfl_xor(m, 2));
        m = fmaxf(m, __shfl_xor(m, 4));
        const float denom = __fadd_rn(m, 1e-6f);
        float nv = tv / denom;               // ONE IEEE divide per table entry
        ntab[tid] = nv;
        uint32_t ub = __float_as_uint(nv);
        htab[tid] = (ub & 0x80000000u) ? ~ub : (ub | 0x80000000u);
    }
    __syncthreads();

    unsigned long long t5[5] = {0ull, 0ull, 0ull, 0ull, 0ull};
#pragma unroll
    for (int j = 0; j < 8; ++j) {
        const int t0 = 4 * tid + 1024 * j;
        const int wi = t0 >> 5;
        const uint32_t wa = words[wi], wp = words[TW + wi], wq = words[2 * TW + wi];
        float4 q;
        float* qp = &q.x;
#pragma unroll
        for (int k = 0; k < 4; ++k) {
            const int sh = 31 - ((t0 & 31) + k);
            const uint32_t idx = ((wa >> sh) & 1u)
                               | (((wp >> sh) & 1u) << 1)
                               | (((wq >> sh) & 1u) << 2);
            qp[k] = ntab[idx];
            unsigned long long key = ((unsigned long long)htab[idx] << 32)
                                   | (unsigned long long)(uint32_t)(TT - 1 - (t0 + k));
            if (key > t5[4]) {
#pragma unroll
                for (int i = 0; i < 5; ++i) {
                    bool g = key > t5[i];
                    unsigned long long o = t5[i];
                    t5[i] = g ? key : o;
                    key   = g ? o : key;
                }
            }
        }
        *reinterpret_cast<float4*>(sal_out + t0) = q;
    }

    float vsum = 0.0f;
    for (int r = 0; r < KWIN; ++r) {
        unsigned long long cand = t5[0];
#pragma unroll
        for (int off = 32; off; off >>= 1) {
            unsigned long long o = __shfl_down(cand, off);
            if (o > cand) cand = o;
        }
        __syncthreads();
        if ((tid & 63) == 0) red[tid >> 6] = cand;
        __syncthreads();
        if (tid == 0) {
            unsigned long long m = red[0];
            if (red[1] > m) m = red[1];
            if (red[2] > m) m = red[2];
            if (red[3] > m) m = red[3];
            wins = m;
        }
        __syncthreads();
        const unsigned long long w = wins;
        if (t5[0] == w) {
            t5[0] = t5[1]; t5[1] = t5[2]; t5[2] = t5[3]; t5[3] = t5[4]; t5[4] = 0ull;
        }
        if (tid == 0) {
            uint32_t hi = (uint32_t)(w >> 32);
            uint32_t fb = (hi & 0x80000000u) ? (hi & 0x7FFFFFFFu) : ~hi;
            vsum += __uint_as_float(fb);
            out[512 + (size_t)BB * TT + (size_t)b * KWIN + r] =
                (float)(int)(TT - 1 - (uint32_t)(w & 0xFFFFFFFFull));
        }
    }

    if (tid == 0) {
        out[b] = 0.5f + 2.0f * tanhf(1.8f * (vsum / 5.0f));
    }
}

extern "C" void kernel_launch(void* const* d_in, const int* in_sizes, int n_in,
                              void* d_out, int out_size, void* d_ws, size_t ws_size,
                              hipStream_t stream) {
    const float* amp      = (const float*)d_in[0];
    const float* pitch    = (const float*)d_in[1];
    const float* boundary = (const float*)d_in[2];
    const float* decay    = (const float*)d_in[3];
    const float* weights  = (const float*)d_in[4];
    float* out = (float*)d_out;

    fused_lif_salience_kernel<<<BB, 256, 0, stream>>>(amp, pitch, boundary,
                                                      decay, weights, out);
}